// Round 5
// baseline (9525.014 us; speedup 1.0000x reference)
//
#include <hip/hip_runtime.h>
#include <cstdint>
#include <cstddef>

// SokobanNCA v5: identical to v4 except __launch_bounds__(256, 2) — restores
// the 256-VGPR cap (2 waves/SIMD min, which LDS forces anyway). v4's regression
// was scratch spill under the implicit 128-VGPR cap (WRITE 672MB, FETCH 10.6GB).

#define NSAMPLES 2048
#define ZROW_BASE 28672          // 112*256
#define HA_OFF 0
#define HB_OFF 28928             // 113*256
#define A1_OFF HB_OFF            // A1 aliases hB (disjoint lifetime)
#define XS_OFF 57600             // HB_OFF + 112*256
#define LDS_TOTAL 62976          // XS_OFF + 112*48

typedef __attribute__((ext_vector_type(8))) short bf16x8;
typedef __attribute__((ext_vector_type(4))) float f32x4;
typedef __attribute__((ext_vector_type(2))) unsigned int u32x2;
typedef __attribute__((ext_vector_type(4))) unsigned int u32x4;

#define MFMA16(A,B,C) __builtin_amdgcn_mfma_f32_16x16x32_bf16((A),(B),(C),0,0,0)

__device__ __forceinline__ unsigned pk2(float a, float b) {
  unsigned r;
  asm("v_cvt_pk_bf16_f32 %0, %1, %2" : "=v"(r) : "v"(a), "v"(b));
  return r;
}
__device__ __forceinline__ unsigned pk2r(float a, float b) {
  return pk2(fmaxf(a, 0.f), fmaxf(b, 0.f));
}

__device__ __forceinline__ short f2bf(float f) {
  unsigned u = __float_as_uint(f);
  return (short)((u + 0x7FFFu + ((u >> 16) & 1u)) >> 16);  // RNE
}

// ---------------- weight pre-pack (unchanged; validated r1-r4) ----------------
__global__ void prepack_kernel(const float* __restrict__ w, short* __restrict__ dst,
                               int mode, int ntc, int Kact, int Nact, int total) {
  int idx = blockIdx.x * 256 + threadIdx.x;
  if (idx >= total) return;
  int j = idx & 7, l = (idx >> 3) & 63, t = idx >> 9;
  int nt = t % ntc, kt = t / ntc;
  int kg = kt * 32 + (l >> 4) * 8 + j;
  int nn = nt * 16 + (l & 15);
  float v = 0.f;
  if (mode == 0) {
    if (kg < Kact && nn < Nact) v = w[nn * Kact + kg];
  } else if (mode == 1) {
    if (kg < 45) { int s = kg / 5, cin = kg - 5 * s; v = w[nn * 45 + cin * 9 + s]; }
  } else {
    int s = kt >> 2;
    int kk = (kt & 3) * 32 + (l >> 4) * 8 + j;
    v = w[nn * 1152 + kk * 9 + s];
  }
  dst[idx] = f2bf(v);
}

// ---------------- device helpers ----------------
__device__ __forceinline__ void load_w4(bf16x8 (&W)[2][4], const short* __restrict__ p,
                                        int w, int l) {
#pragma unroll
  for (int mt = 0; mt < 2; ++mt)
#pragma unroll
    for (int kt = 0; kt < 4; ++kt)
      W[mt][kt] = *(const bf16x8*)&p[((kt * 8 + 2 * w + mt) * 64 + l) * 8];
}
__device__ __forceinline__ void load_w2(bf16x8 (&W)[2][2], const short* __restrict__ p,
                                        int w, int l) {
#pragma unroll
  for (int mt = 0; mt < 2; ++mt)
#pragma unroll
    for (int kt = 0; kt < 2; ++kt)
      W[mt][kt] = *(const bf16x8*)&p[((kt * 8 + 2 * w + mt) * 64 + l) * 8];
}
__device__ __forceinline__ void load_b(f32x4 (&pb)[2], const float* __restrict__ bp,
                                       int w, int g) {
  pb[0] = *(const f32x4*)&bp[16 * (2 * w) + 4 * g];
  pb[1] = *(const f32x4*)&bp[16 * (2 * w + 1) + 4 * g];
}

__device__ __forceinline__ void chain_mfma(const bf16x8 (&W)[2][4], const f32x4 (&pb)[2],
                                           const char* lds, int rdb, f32x4 (&acc)[2][7]) {
#pragma unroll
  for (int qt = 0; qt < 7; ++qt) { acc[0][qt] = pb[0]; acc[1][qt] = pb[1]; }
#pragma unroll
  for (int kt = 0; kt < 4; ++kt) {
    const char* src = lds + (rdb ^ (kt << 6));
#pragma unroll
    for (int qt = 0; qt < 7; ++qt) {
      bf16x8 Bf = *(const bf16x8*)(src + qt * 4096);
      acc[0][qt] = MFMA16(W[0][kt], Bf, acc[0][qt]);
      acc[1][qt] = MFMA16(W[1][kt], Bf, acc[1][qt]);
    }
  }
}

__device__ __forceinline__ void store_h(const f32x4 (&acc)[2][7], char* lds,
                                        int wb0, int wb1) {
#pragma unroll
  for (int mt = 0; mt < 2; ++mt) {
    char* d = lds + (mt ? wb1 : wb0);
#pragma unroll
    for (int qt = 0; qt < 7; ++qt) {
      f32x4 v = acc[mt][qt];
      u32x2 wv = {pk2r(v.x, v.y), pk2r(v.z, v.w)};
      *(u32x2*)(d + qt * 4096) = wv;
    }
  }
}

__device__ __forceinline__ void c2_slice(const bf16x8 (&W)[2][4], f32x4 (&acc)[2][7],
                                         const char* lds, const int (&rc)[7],
                                         const int (&zadj)[7], int n, int g16, int s) {
  const int dr = s / 3 - 1, dc = s % 3 - 1;
  const int ps = n + dr * 10 + dc;
  const int bs = HA_OFF + ps * 256 + (g16 ^ ((ps & 7) << 4));
#pragma unroll
  for (int qt = 0; qt < 7; ++qt) {
    bool ok = ((unsigned)((rc[qt] >> 5) + dr) < 10u) &&
              ((unsigned)((rc[qt] & 31) + dc) < 10u);
    int va = ok ? bs : zadj[qt];
#pragma unroll
    for (int kt = 0; kt < 4; ++kt) {
      bf16x8 Bf = *(const bf16x8*)(lds + (va ^ (kt << 6)) + qt * 4096);
      acc[0][qt] = MFMA16(W[0][kt], Bf, acc[0][qt]);
      acc[1][qt] = MFMA16(W[1][kt], Bf, acc[1][qt]);
    }
  }
}

// ---------------- main kernel ----------------
__global__ __launch_bounds__(256, 2)
void nca_kernel(
    const float* __restrict__ x_in,
    const float* __restrict__ b1p, const float* __restrict__ b2p,
    const float* __restrict__ b3p, const float* __restrict__ b4p,
    const float* __restrict__ b5p, const float* __restrict__ b6p,
    const float* __restrict__ b7p,
    const short* __restrict__ W1, const short* __restrict__ W2,
    const short* __restrict__ W3,   // W3..W6 contiguous: W3 + li*16384
    const short* __restrict__ W7,
    const int* __restrict__ steps_ptr, float* __restrict__ d_out) {
  __shared__ __align__(16) char lds[LDS_TOTAL];
  float* xs = (float*)(lds + XS_OFF);  // [112][12] f32, rows 48 B

  const int tid = threadIdx.x;
  const int sample = blockIdx.x;
  const int w = tid >> 6;
  const int l = tid & 63;
  const int n = l & 15;
  const int g = l >> 4;
  const int g16 = g << 4;
  const int swzc = (n & 7) << 4;
  const int steps = *steps_ptr;
  const float steps_f = (float)steps;
  const f32x4 fz = {0.f, 0.f, 0.f, 0.f};

  // loop-invariant LDS address bases (layout identical to r3/r4)
  const int rdA = HA_OFF + n * 256 + (g16 ^ swzc);
  const int rdB = HB_OFF + n * 256 + (g16 ^ swzc);
  const int rd1 = A1_OFF + n * 128 + (g16 ^ swzc);
  const int wcol0 = ((64 * w) | (8 * g)) ^ swzc;
  const int wcol1 = ((64 * w + 32) | (8 * g)) ^ swzc;
  const int wbA0 = HA_OFF + n * 256 + wcol0, wbA1 = HA_OFF + n * 256 + wcol1;
  const int wbB0 = HB_OFF + n * 256 + wcol0, wbB1 = HB_OFF + n * 256 + wcol1;
  int zadj[7];
#pragma unroll
  for (int qt = 0; qt < 7; ++qt) zadj[qt] = HA_OFF + ZROW_BASE + g16 - 4096 * qt;

  // per-lane pixel geometry per q-tile
  int rc[7];
#pragma unroll
  for (int qt = 0; qt < 7; ++qt) {
    int p = 16 * qt + n;
    if (p < 100) { int r = p / 10; rc[qt] = r * 32 + (p - 10 * r); }
    else rc[qt] = 0x4000;
  }
  // strided (c,px) decomposition for 500-elem copies
  const int cA = tid / 100, pA = tid - 100 * cA;
  const int cB = (tid + 256) / 100, pB = tid + 256 - 100 * cB;
  const int offA = pA * 12 + cA, offB = pB * 12 + cB;

  // zero ZROW of hA
  if (tid < 64) *(unsigned*)(lds + HA_OFF + ZROW_BASE + tid * 4) = 0;
  // load x state
  xs[offA] = x_in[(size_t)sample * 500 + tid];
  if (tid < 244) xs[offB] = x_in[(size_t)sample * 500 + tid + 256];
  // resident c7 bias
  f32x4 b7v = fz;
  if (g == 0) b7v = *(const f32x4*)&b7p[0];
  else if (g == 1) b7v.x = b7p[4];
  __syncthreads();

  // weight/bias staging registers (transient, reloaded per phase)
  bf16x8 Wa[2][4], Wb[2][4], Wc1[2][2], W7f[4];
  f32x4 pbc1[2], pbc2[2], pbN[2];

  for (int step = 0; step < steps; ++step) {
    // ---- phase A: prefetch c1 + c2s0 weights; copy out states[step-1]; im2col ----
    load_w2(Wc1, W1, w, l);
    load_b(pbc1, b1p, w, g);
    load_w4(Wa, W2, w, l);          // c2 slice 0
    load_b(pbc2, b2p, w, g);
    if (step > 0) {
      size_t sb = 1024000u + ((size_t)(step - 1) * NSAMPLES + sample) * 500u;
      __builtin_nontemporal_store(xs[offA], &d_out[sb + tid]);
      if (tid < 244) __builtin_nontemporal_store(xs[offB], &d_out[sb + tid + 256]);
    }
    if (tid < 112) {
      const int p = tid;
      const bool pv = p < 100;
      const int pc = pv ? p : 99;
      const int r = pc / 10, c0 = pc - 10 * r;
      float val[48];
#pragma unroll
      for (int s = 0; s < 9; ++s) {
        const int dr = s / 3 - 1, dc = s % 3 - 1;
        f32x4 xv = fz; float x4v = 0.f;
        if (pv && (unsigned)(r + dr) < 10u && (unsigned)(c0 + dc) < 10u) {
          const float* xr = &xs[(p + dr * 10 + dc) * 12];
          xv = *(const f32x4*)xr; x4v = xr[4];
        }
        val[5*s+0] = xv.x; val[5*s+1] = xv.y; val[5*s+2] = xv.z;
        val[5*s+3] = xv.w; val[5*s+4] = x4v;
      }
      val[45] = val[46] = val[47] = 0.f;
      unsigned wd[24];
#pragma unroll
      for (int i = 0; i < 24; ++i) wd[i] = pk2(val[2*i], val[2*i+1]);
      const int swzr = (p & 7) << 4;
      char* arow = lds + A1_OFF + p * 128;
#pragma unroll
      for (int j = 0; j < 6; ++j) {
        u32x4 wv = {wd[4*j], wd[4*j+1], wd[4*j+2], wd[4*j+3]};
        *(u32x4*)(arow + ((16 * j) ^ swzr)) = wv;
      }
      u32x4 z4 = {0, 0, 0, 0};
      *(u32x4*)(arow + (96 ^ swzr)) = z4;
      *(u32x4*)(arow + (112 ^ swzr)) = z4;
    }
    __syncthreads();

    // ---- c1: A1 @ W1 (K=64) -> hA ; prefetch c2 slice 1 ----
    {
      load_w4(Wb, W2 + 16384, w, l);  // slice 1
      f32x4 acc[2][7];
#pragma unroll
      for (int qt = 0; qt < 7; ++qt) { acc[0][qt] = pbc1[0]; acc[1][qt] = pbc1[1]; }
#pragma unroll
      for (int kt = 0; kt < 2; ++kt) {
        const char* src = lds + (rd1 ^ (kt << 6));
#pragma unroll
        for (int qt = 0; qt < 7; ++qt) {
          bf16x8 Bf = *(const bf16x8*)(src + qt * 2048);
          acc[0][qt] = MFMA16(Wc1[0][kt], Bf, acc[0][qt]);
          acc[1][qt] = MFMA16(Wc1[1][kt], Bf, acc[1][qt]);
        }
      }
      store_h(acc, lds, wbA0, wbA1);
    }
    __syncthreads();

    // ---- c2: 9 shift-slices, 2-deep weight double-buffer ----
    {
      f32x4 acc[2][7];
#pragma unroll
      for (int qt = 0; qt < 7; ++qt) { acc[0][qt] = pbc2[0]; acc[1][qt] = pbc2[1]; }
      c2_slice(Wa, acc, lds, rc, zadj, n, g16, 0); load_w4(Wa, W2 + 2 * 16384, w, l);
      c2_slice(Wb, acc, lds, rc, zadj, n, g16, 1); load_w4(Wb, W2 + 3 * 16384, w, l);
      c2_slice(Wa, acc, lds, rc, zadj, n, g16, 2); load_w4(Wa, W2 + 4 * 16384, w, l);
      c2_slice(Wb, acc, lds, rc, zadj, n, g16, 3); load_w4(Wb, W2 + 5 * 16384, w, l);
      c2_slice(Wa, acc, lds, rc, zadj, n, g16, 4); load_w4(Wa, W2 + 6 * 16384, w, l);
      c2_slice(Wb, acc, lds, rc, zadj, n, g16, 5); load_w4(Wb, W2 + 7 * 16384, w, l);
      c2_slice(Wa, acc, lds, rc, zadj, n, g16, 6); load_w4(Wa, W2 + 8 * 16384, w, l);
      c2_slice(Wb, acc, lds, rc, zadj, n, g16, 7);
      load_w4(Wb, W3, w, l); load_b(pbN, b3p, w, g);   // prefetch c3
      c2_slice(Wa, acc, lds, rc, zadj, n, g16, 8);
      store_h(acc, lds, wbB0, wbB1);
    }
    __syncthreads();

    // ---- c3: hB -> hA (W3 in Wb) ; prefetch c4 ----
    {
      load_w4(Wa, W3 + 16384, w, l); load_b(pbc2, b4p, w, g);
      f32x4 acc[2][7];
      chain_mfma(Wb, pbN, lds, rdB, acc);
      store_h(acc, lds, wbA0, wbA1);
    }
    __syncthreads();
    // ---- c4: hA -> hB (W4 in Wa) ; prefetch c5 ----
    {
      load_w4(Wb, W3 + 2 * 16384, w, l); load_b(pbN, b5p, w, g);
      f32x4 acc[2][7];
      chain_mfma(Wa, pbc2, lds, rdA, acc);
      store_h(acc, lds, wbB0, wbB1);
    }
    __syncthreads();
    // ---- c5: hB -> hA (W5 in Wb) ; prefetch c6 ----
    {
      load_w4(Wa, W3 + 3 * 16384, w, l); load_b(pbc2, b6p, w, g);
      f32x4 acc[2][7];
      chain_mfma(Wb, pbN, lds, rdB, acc);
      store_h(acc, lds, wbA0, wbA1);
    }
    __syncthreads();
    // ---- c6: hA -> hB (W6 in Wa) ; prefetch c7 weights ----
    {
#pragma unroll
      for (int kt = 0; kt < 4; ++kt)
        W7f[kt] = *(const bf16x8*)&W7[(kt * 64 + l) * 8];
      f32x4 acc[2][7];
      chain_mfma(Wa, pbc2, lds, rdA, acc);
      store_h(acc, lds, wbB0, wbB1);
    }
    __syncthreads();

    // ---- c7 (128->5) + residual + softmax ----
    {
      float invT = 1.f / fmaxf(1.f - (float)step / steps_f, 0.5f);
#pragma unroll
      for (int rep = 0; rep < 2; ++rep) {
        int qt = 2 * w + rep;
        if (qt < 7) {
          f32x4 a = b7v;
          int va7 = rdB + qt * 4096;
#pragma unroll
          for (int kt = 0; kt < 4; ++kt) {
            bf16x8 Bf = *(const bf16x8*)(lds + (va7 ^ (kt << 6)));
            a = MFMA16(W7f[kt], Bf, a);
          }
          float c4v = __shfl_xor(a.x, 16);
          int px = 16 * qt + n;
          if (g == 0 && px < 100) {
            float* xr = &xs[px * 12];
            f32x4 xo = *(f32x4*)xr; float x4 = xr[4];
            float v0 = (xo.x + a.x) * invT, v1 = (xo.y + a.y) * invT;
            float v2 = (xo.z + a.z) * invT, v3 = (xo.w + a.w) * invT;
            float v4 = (x4 + c4v) * invT;
            float m = fmaxf(fmaxf(fmaxf(v0, v1), fmaxf(v2, v3)), v4);
            float e0 = __expf(v0 - m), e1 = __expf(v1 - m), e2 = __expf(v2 - m);
            float e3 = __expf(v3 - m), e4 = __expf(v4 - m);
            float inv = 1.f / (e0 + e1 + e2 + e3 + e4);
            f32x4 pv = {e0 * inv, e1 * inv, e2 * inv, e3 * inv};
            *(f32x4*)xr = pv; xr[4] = e4 * inv;
          }
        }
      }
    }
    __syncthreads();
  }

  // ---- final outputs: x_final + states[steps-1] (nontemporal) ----
  {
    size_t sb = 1024000u + ((size_t)(steps - 1) * NSAMPLES + sample) * 500u;
    size_t fb = (size_t)sample * 500u;
    float vA = xs[offA];
    __builtin_nontemporal_store(vA, &d_out[fb + tid]);
    __builtin_nontemporal_store(vA, &d_out[sb + tid]);
    if (tid < 244) {
      float vB = xs[offB];
      __builtin_nontemporal_store(vB, &d_out[fb + tid + 256]);
      __builtin_nontemporal_store(vB, &d_out[sb + tid + 256]);
    }
  }
}

// ---------------- launch ----------------
extern "C" void kernel_launch(void* const* d_in, const int* in_sizes, int n_in,
                              void* d_out, int out_size, void* d_ws, size_t ws_size,
                              hipStream_t stream) {
  const float* x   = (const float*)d_in[0];
  const float* wp1 = (const float*)d_in[1];
  const float* bp1 = (const float*)d_in[2];
  const float* wp2 = (const float*)d_in[3];
  const float* bp2 = (const float*)d_in[4];
  const float* wp3 = (const float*)d_in[5];
  const float* bp3 = (const float*)d_in[6];
  const float* wu1 = (const float*)d_in[7];
  const float* bu1 = (const float*)d_in[8];
  const float* wu2 = (const float*)d_in[9];
  const float* bu2 = (const float*)d_in[10];
  const float* wu3 = (const float*)d_in[11];
  const float* bu3 = (const float*)d_in[12];
  const float* wu4 = (const float*)d_in[13];
  const float* bu4 = (const float*)d_in[14];
  const int* steps = (const int*)d_in[15];

  short* W1 = (short*)d_ws;          // [2][8][512]
  short* W2 = W1 + 8192;             // [36][8][512]
  short* W3 = W2 + 147456;           // 4 x [4][8][512] contiguous
  short* W4 = W3 + 16384;
  short* W5 = W4 + 16384;
  short* W6 = W5 + 16384;
  short* W7 = W6 + 16384;            // [4][1][512]

  prepack_kernel<<<(8192   + 255) / 256, 256, 0, stream>>>(wp1, W1, 1, 8, 45,   128, 8192);
  prepack_kernel<<<(147456 + 255) / 256, 256, 0, stream>>>(wp2, W2, 2, 8, 1152, 128, 147456);
  prepack_kernel<<<(16384  + 255) / 256, 256, 0, stream>>>(wp3, W3, 0, 8, 128,  128, 16384);
  prepack_kernel<<<(16384  + 255) / 256, 256, 0, stream>>>(wu1, W4, 0, 8, 128,  128, 16384);
  prepack_kernel<<<(16384  + 255) / 256, 256, 0, stream>>>(wu2, W5, 0, 8, 128,  128, 16384);
  prepack_kernel<<<(16384  + 255) / 256, 256, 0, stream>>>(wu3, W6, 0, 8, 128,  128, 16384);
  prepack_kernel<<<(2048   + 255) / 256, 256, 0, stream>>>(wu4, W7, 0, 1, 128,  5,   2048);

  nca_kernel<<<NSAMPLES, 256, 0, stream>>>(
      x, bp1, bp2, bp3, bu1, bu2, bu3, bu4,
      W1, W2, W3, W7, steps, (float*)d_out);
}

// Round 6
// 4583.435 us; speedup vs baseline: 2.0781x; 2.0781x over previous
//
#include <hip/hip_runtime.h>
#include <cstdint>
#include <cstddef>

// SokobanNCA v6: r3's transient weight loading (proven 120 VGPR, no spill)
// + r4's pk2 (v_cvt_pk_bf16_f32) packing and hoisted XOR LDS addressing.
// No cross-barrier weight registers -> fits the 128-VGPR allocation the
// compiler insists on (r4/r5 spilled: WRITE 672MB, FETCH 10.6GB).

#define NSAMPLES 2048
#define ZROW_BASE 28672          // 112*256
#define HA_OFF 0
#define HB_OFF 28928             // 113*256
#define A1_OFF HB_OFF            // A1 aliases hB (disjoint lifetime)
#define XS_OFF 57600             // HB_OFF + 112*256
#define LDS_TOTAL 62976          // XS_OFF + 112*48

typedef __attribute__((ext_vector_type(8))) short bf16x8;
typedef __attribute__((ext_vector_type(4))) float f32x4;
typedef __attribute__((ext_vector_type(2))) unsigned int u32x2;
typedef __attribute__((ext_vector_type(4))) unsigned int u32x4;

#define MFMA16(A,B,C) __builtin_amdgcn_mfma_f32_16x16x32_bf16((A),(B),(C),0,0,0)

__device__ __forceinline__ unsigned pk2(float a, float b) {
  unsigned r;
  asm("v_cvt_pk_bf16_f32 %0, %1, %2" : "=v"(r) : "v"(a), "v"(b));
  return r;
}
__device__ __forceinline__ unsigned pk2r(float a, float b) {
  return pk2(fmaxf(a, 0.f), fmaxf(b, 0.f));
}

__device__ __forceinline__ short f2bf(float f) {
  unsigned u = __float_as_uint(f);
  return (short)((u + 0x7FFFu + ((u >> 16) & 1u)) >> 16);  // RNE
}

// ---------------- weight pre-pack (unchanged; validated r1-r5) ----------------
__global__ void prepack_kernel(const float* __restrict__ w, short* __restrict__ dst,
                               int mode, int ntc, int Kact, int Nact, int total) {
  int idx = blockIdx.x * 256 + threadIdx.x;
  if (idx >= total) return;
  int j = idx & 7, l = (idx >> 3) & 63, t = idx >> 9;
  int nt = t % ntc, kt = t / ntc;
  int kg = kt * 32 + (l >> 4) * 8 + j;
  int nn = nt * 16 + (l & 15);
  float v = 0.f;
  if (mode == 0) {
    if (kg < Kact && nn < Nact) v = w[nn * Kact + kg];
  } else if (mode == 1) {
    if (kg < 45) { int s = kg / 5, cin = kg - 5 * s; v = w[nn * 45 + cin * 9 + s]; }
  } else {
    int s = kt >> 2;
    int kk = (kt & 3) * 32 + (l >> 4) * 8 + j;
    v = w[nn * 1152 + kk * 9 + s];
  }
  dst[idx] = f2bf(v);
}

// ---------------- device helpers ----------------
__device__ __forceinline__ void load_w4(bf16x8 (&W)[2][4], const short* __restrict__ p,
                                        int w, int l) {
#pragma unroll
  for (int mt = 0; mt < 2; ++mt)
#pragma unroll
    for (int kt = 0; kt < 4; ++kt)
      W[mt][kt] = *(const bf16x8*)&p[((kt * 8 + 2 * w + mt) * 64 + l) * 8];
}
__device__ __forceinline__ void load_b(f32x4 (&pb)[2], const float* __restrict__ bp,
                                       int w, int g) {
  pb[0] = *(const f32x4*)&bp[16 * (2 * w) + 4 * g];
  pb[1] = *(const f32x4*)&bp[16 * (2 * w + 1) + 4 * g];
}

__device__ __forceinline__ void chain_mfma(const bf16x8 (&W)[2][4], const f32x4 (&pb)[2],
                                           const char* lds, int rdb, f32x4 (&acc)[2][7]) {
#pragma unroll
  for (int qt = 0; qt < 7; ++qt) { acc[0][qt] = pb[0]; acc[1][qt] = pb[1]; }
#pragma unroll
  for (int kt = 0; kt < 4; ++kt) {
    const char* src = lds + (rdb ^ (kt << 6));
#pragma unroll
    for (int qt = 0; qt < 7; ++qt) {
      bf16x8 Bf = *(const bf16x8*)(src + qt * 4096);
      acc[0][qt] = MFMA16(W[0][kt], Bf, acc[0][qt]);
      acc[1][qt] = MFMA16(W[1][kt], Bf, acc[1][qt]);
    }
  }
}

__device__ __forceinline__ void store_h(const f32x4 (&acc)[2][7], char* lds,
                                        int wb0, int wb1) {
#pragma unroll
  for (int mt = 0; mt < 2; ++mt) {
    char* d = lds + (mt ? wb1 : wb0);
#pragma unroll
    for (int qt = 0; qt < 7; ++qt) {
      f32x4 v = acc[mt][qt];
      u32x2 wv = {pk2r(v.x, v.y), pk2r(v.z, v.w)};
      *(u32x2*)(d + qt * 4096) = wv;
    }
  }
}

// ---------------- main kernel ----------------
__global__ __launch_bounds__(256, 2)
void nca_kernel(
    const float* __restrict__ x_in,
    const float* __restrict__ b1p, const float* __restrict__ b2p,
    const float* __restrict__ b3p, const float* __restrict__ b4p,
    const float* __restrict__ b5p, const float* __restrict__ b6p,
    const float* __restrict__ b7p,
    const short* __restrict__ W1, const short* __restrict__ W2,
    const short* __restrict__ W3,   // W3..W6 contiguous: W3 + li*16384
    const short* __restrict__ W7,
    const int* __restrict__ steps_ptr, float* __restrict__ d_out) {
  __shared__ __align__(16) char lds[LDS_TOTAL];
  float* xs = (float*)(lds + XS_OFF);  // [112][12] f32, rows 48 B

  const int tid = threadIdx.x;
  const int sample = blockIdx.x;
  const int w = tid >> 6;
  const int l = tid & 63;
  const int n = l & 15;
  const int g = l >> 4;
  const int g16 = g << 4;
  const int swzc = (n & 7) << 4;
  const int steps = *steps_ptr;
  const float steps_f = (float)steps;
  const f32x4 fz = {0.f, 0.f, 0.f, 0.f};

  // loop-invariant LDS address bases (layout identical to r3-r5)
  const int rdA = HA_OFF + n * 256 + (g16 ^ swzc);
  const int rdB = HB_OFF + n * 256 + (g16 ^ swzc);
  const int rd1 = A1_OFF + n * 128 + (g16 ^ swzc);
  const int wcol0 = ((64 * w) | (8 * g)) ^ swzc;
  const int wcol1 = ((64 * w + 32) | (8 * g)) ^ swzc;
  const int wbA0 = HA_OFF + n * 256 + wcol0, wbA1 = HA_OFF + n * 256 + wcol1;
  const int wbB0 = HB_OFF + n * 256 + wcol0, wbB1 = HB_OFF + n * 256 + wcol1;
  int zadj[7];
#pragma unroll
  for (int qt = 0; qt < 7; ++qt) zadj[qt] = HA_OFF + ZROW_BASE + g16 - 4096 * qt;

  // per-lane pixel geometry per q-tile
  int rc[7];
#pragma unroll
  for (int qt = 0; qt < 7; ++qt) {
    int p = 16 * qt + n;
    if (p < 100) { int r = p / 10; rc[qt] = r * 32 + (p - 10 * r); }
    else rc[qt] = 0x4000;
  }
  // strided (c,px) decomposition for 500-elem copies
  const int cA = tid / 100, pA = tid - 100 * cA;
  const int cB = (tid + 256) / 100, pB = tid + 256 - 100 * cB;
  const int offA = pA * 12 + cA, offB = pB * 12 + cB;

  // zero ZROW of hA
  if (tid < 64) *(unsigned*)(lds + HA_OFF + ZROW_BASE + tid * 4) = 0;
  // load x state
  xs[offA] = x_in[(size_t)sample * 500 + tid];
  if (tid < 244) xs[offB] = x_in[(size_t)sample * 500 + tid + 256];
  // resident c7 bias
  f32x4 b7v = fz;
  if (g == 0) b7v = *(const f32x4*)&b7p[0];
  else if (g == 1) b7v.x = b7p[4];
  __syncthreads();

  for (int step = 0; step < steps; ++step) {
    // ---- phase A: copy out states[step-1]; build im2col ----
    if (step > 0) {
      size_t sb = 1024000u + ((size_t)(step - 1) * NSAMPLES + sample) * 500u;
      __builtin_nontemporal_store(xs[offA], &d_out[sb + tid]);
      if (tid < 244) __builtin_nontemporal_store(xs[offB], &d_out[sb + tid + 256]);
    }
    if (tid < 112) {
      const int p = tid;
      const bool pv = p < 100;
      const int pc = pv ? p : 99;
      const int r = pc / 10, c0 = pc - 10 * r;
      float val[48];
#pragma unroll
      for (int s = 0; s < 9; ++s) {
        const int dr = s / 3 - 1, dc = s % 3 - 1;
        f32x4 xv = fz; float x4v = 0.f;
        if (pv && (unsigned)(r + dr) < 10u && (unsigned)(c0 + dc) < 10u) {
          const float* xr = &xs[(p + dr * 10 + dc) * 12];
          xv = *(const f32x4*)xr; x4v = xr[4];
        }
        val[5*s+0] = xv.x; val[5*s+1] = xv.y; val[5*s+2] = xv.z;
        val[5*s+3] = xv.w; val[5*s+4] = x4v;
      }
      val[45] = val[46] = val[47] = 0.f;
      unsigned wd[24];
#pragma unroll
      for (int i = 0; i < 24; ++i) wd[i] = pk2(val[2*i], val[2*i+1]);
      const int swzr = (p & 7) << 4;
      char* arow = lds + A1_OFF + p * 128;
#pragma unroll
      for (int j = 0; j < 6; ++j) {
        u32x4 wv = {wd[4*j], wd[4*j+1], wd[4*j+2], wd[4*j+3]};
        *(u32x4*)(arow + ((16 * j) ^ swzr)) = wv;
      }
      u32x4 z4 = {0, 0, 0, 0};
      *(u32x4*)(arow + (96 ^ swzr)) = z4;
      *(u32x4*)(arow + (112 ^ swzr)) = z4;
    }
    __syncthreads();

    // ---- c1: A1 @ W1 (K=64) -> hA, transient weights ----
    {
      bf16x8 Wf[2][2];
#pragma unroll
      for (int mt = 0; mt < 2; ++mt)
#pragma unroll
        for (int kt = 0; kt < 2; ++kt)
          Wf[mt][kt] = *(const bf16x8*)&W1[((kt * 8 + 2 * w + mt) * 64 + l) * 8];
      f32x4 pb[2];
      load_b(pb, b1p, w, g);
      f32x4 acc[2][7];
#pragma unroll
      for (int qt = 0; qt < 7; ++qt) { acc[0][qt] = pb[0]; acc[1][qt] = pb[1]; }
#pragma unroll
      for (int kt = 0; kt < 2; ++kt) {
        const char* src = lds + (rd1 ^ (kt << 6));
#pragma unroll
        for (int qt = 0; qt < 7; ++qt) {
          bf16x8 Bf = *(const bf16x8*)(src + qt * 2048);
          acc[0][qt] = MFMA16(Wf[0][kt], Bf, acc[0][qt]);
          acc[1][qt] = MFMA16(Wf[1][kt], Bf, acc[1][qt]);
        }
      }
      store_h(acc, lds, wbA0, wbA1);
    }
    __syncthreads();

    // ---- c2: 3x3 shift-decomposed, RUNTIME s-loop, transient weights ----
    {
      f32x4 acc[2][7];
      {
        f32x4 pb[2];
        load_b(pb, b2p, w, g);
#pragma unroll
        for (int qt = 0; qt < 7; ++qt) { acc[0][qt] = pb[0]; acc[1][qt] = pb[1]; }
      }
#pragma unroll 1
      for (int s = 0; s < 9; ++s) {
        const int s3 = s / 3;
        const int dr = s3 - 1, dc = s - 3 * s3 - 1;
        bf16x8 Wf[2][4];
        load_w4(Wf, W2 + s * 16384, w, l);
        const int ps = n + dr * 10 + dc;
        const int bs = HA_OFF + ps * 256 + (g16 ^ ((ps & 7) << 4));
#pragma unroll
        for (int qt = 0; qt < 7; ++qt) {
          bool ok = ((unsigned)((rc[qt] >> 5) + dr) < 10u) &&
                    ((unsigned)((rc[qt] & 31) + dc) < 10u);
          int va = ok ? bs : zadj[qt];
#pragma unroll
          for (int kt = 0; kt < 4; ++kt) {
            bf16x8 Bf = *(const bf16x8*)(lds + (va ^ (kt << 6)) + qt * 4096);
            acc[0][qt] = MFMA16(Wf[0][kt], Bf, acc[0][qt]);
            acc[1][qt] = MFMA16(Wf[1][kt], Bf, acc[1][qt]);
          }
        }
      }
      store_h(acc, lds, wbB0, wbB1);
    }
    __syncthreads();

    // ---- c3..c6: RUNTIME layer loop, ping-pong hB<->hA, transient weights ----
#pragma unroll 1
    for (int li = 0; li < 4; ++li) {
      const float* bp = (li == 0) ? b3p : (li == 1) ? b4p : (li == 2) ? b5p : b6p;
      const int rdb = (li & 1) ? rdA : rdB;
      const int wb0 = (li & 1) ? wbB0 : wbA0;
      const int wb1 = (li & 1) ? wbB1 : wbA1;
      bf16x8 Wf[2][4];
      load_w4(Wf, W3 + li * 16384, w, l);
      f32x4 pb[2];
      load_b(pb, bp, w, g);
      f32x4 acc[2][7];
      chain_mfma(Wf, pb, lds, rdb, acc);
      store_h(acc, lds, wb0, wb1);
      __syncthreads();
    }

    // ---- c7 (128->5) + residual + softmax ----
    {
      bf16x8 W7f[4];
#pragma unroll
      for (int kt = 0; kt < 4; ++kt)
        W7f[kt] = *(const bf16x8*)&W7[(kt * 64 + l) * 8];
      float invT = 1.f / fmaxf(1.f - (float)step / steps_f, 0.5f);
#pragma unroll
      for (int rep = 0; rep < 2; ++rep) {
        int qt = 2 * w + rep;
        if (qt < 7) {
          f32x4 a = b7v;
          int va7 = rdB + qt * 4096;
#pragma unroll
          for (int kt = 0; kt < 4; ++kt) {
            bf16x8 Bf = *(const bf16x8*)(lds + (va7 ^ (kt << 6)));
            a = MFMA16(W7f[kt], Bf, a);
          }
          float c4v = __shfl_xor(a.x, 16);
          int px = 16 * qt + n;
          if (g == 0 && px < 100) {
            float* xr = &xs[px * 12];
            f32x4 xo = *(f32x4*)xr; float x4 = xr[4];
            float v0 = (xo.x + a.x) * invT, v1 = (xo.y + a.y) * invT;
            float v2 = (xo.z + a.z) * invT, v3 = (xo.w + a.w) * invT;
            float v4 = (x4 + c4v) * invT;
            float m = fmaxf(fmaxf(fmaxf(v0, v1), fmaxf(v2, v3)), v4);
            float e0 = __expf(v0 - m), e1 = __expf(v1 - m), e2 = __expf(v2 - m);
            float e3 = __expf(v3 - m), e4 = __expf(v4 - m);
            float inv = 1.f / (e0 + e1 + e2 + e3 + e4);
            f32x4 pv = {e0 * inv, e1 * inv, e2 * inv, e3 * inv};
            *(f32x4*)xr = pv; xr[4] = e4 * inv;
          }
        }
      }
    }
    __syncthreads();
  }

  // ---- final outputs: x_final + states[steps-1] (nontemporal) ----
  {
    size_t sb = 1024000u + ((size_t)(steps - 1) * NSAMPLES + sample) * 500u;
    size_t fb = (size_t)sample * 500u;
    float vA = xs[offA];
    __builtin_nontemporal_store(vA, &d_out[fb + tid]);
    __builtin_nontemporal_store(vA, &d_out[sb + tid]);
    if (tid < 244) {
      float vB = xs[offB];
      __builtin_nontemporal_store(vB, &d_out[fb + tid + 256]);
      __builtin_nontemporal_store(vB, &d_out[sb + tid + 256]);
    }
  }
}

// ---------------- launch ----------------
extern "C" void kernel_launch(void* const* d_in, const int* in_sizes, int n_in,
                              void* d_out, int out_size, void* d_ws, size_t ws_size,
                              hipStream_t stream) {
  const float* x   = (const float*)d_in[0];
  const float* wp1 = (const float*)d_in[1];
  const float* bp1 = (const float*)d_in[2];
  const float* wp2 = (const float*)d_in[3];
  const float* bp2 = (const float*)d_in[4];
  const float* wp3 = (const float*)d_in[5];
  const float* bp3 = (const float*)d_in[6];
  const float* wu1 = (const float*)d_in[7];
  const float* bu1 = (const float*)d_in[8];
  const float* wu2 = (const float*)d_in[9];
  const float* bu2 = (const float*)d_in[10];
  const float* wu3 = (const float*)d_in[11];
  const float* bu3 = (const float*)d_in[12];
  const float* wu4 = (const float*)d_in[13];
  const float* bu4 = (const float*)d_in[14];
  const int* steps = (const int*)d_in[15];

  short* W1 = (short*)d_ws;          // [2][8][512]
  short* W2 = W1 + 8192;             // [36][8][512]
  short* W3 = W2 + 147456;           // 4 x [4][8][512] contiguous
  short* W4 = W3 + 16384;
  short* W5 = W4 + 16384;
  short* W6 = W5 + 16384;
  short* W7 = W6 + 16384;            // [4][1][512]

  prepack_kernel<<<(8192   + 255) / 256, 256, 0, stream>>>(wp1, W1, 1, 8, 45,   128, 8192);
  prepack_kernel<<<(147456 + 255) / 256, 256, 0, stream>>>(wp2, W2, 2, 8, 1152, 128, 147456);
  prepack_kernel<<<(16384  + 255) / 256, 256, 0, stream>>>(wp3, W3, 0, 8, 128,  128, 16384);
  prepack_kernel<<<(16384  + 255) / 256, 256, 0, stream>>>(wu1, W4, 0, 8, 128,  128, 16384);
  prepack_kernel<<<(16384  + 255) / 256, 256, 0, stream>>>(wu2, W5, 0, 8, 128,  128, 16384);
  prepack_kernel<<<(16384  + 255) / 256, 256, 0, stream>>>(wu3, W6, 0, 8, 128,  128, 16384);
  prepack_kernel<<<(2048   + 255) / 256, 256, 0, stream>>>(wu4, W7, 0, 1, 128,  5,   2048);

  nca_kernel<<<NSAMPLES, 256, 0, stream>>>(
      x, bp1, bp2, bp3, bu1, bu2, bu3, bu4,
      W1, W2, W3, W7, steps, (float*)d_out);
}